// Round 2
// baseline (15516.983 us; speedup 1.0000x reference)
//
#include <hip/hip_runtime.h>
#include <hip/hip_fp16.h>

// GRUPK R12: co-resident L0+L1 recurrence with per-role soft barriers.
// R11 evidence: step = 3680cy, per-SIMD issue only ~1270cy -> ~65% dep-stall;
// 2 waves/SIMD in lockstep (same block/barrier) can't fill each other's holes.
// R12: (1) 32 fat recur blocks (1024 thr): waves 0-7 = L0@k, waves 8-15 = L1@k-2
//     -> 4 waves/SIMD, roles decoupled via LDS counting barriers (no s_barrier in
//     the step loop) so anti-phase drift fills dep stalls dynamically.
// (2) hout stored directly from hreg (half4/lane, coalesced) - removes the
//     per-step LDS write->read roundtrip from the recur critical path. B1 now
//     stages its 32KB hout slab into LDS (padded stride 264) and transposes there
//     (B1 has large slack).
// (3) B0/B1 adapted to 1024-thread blocks. Grid 192 = 32 recur + 32 B0 + 128 B1.
//
// ws layout (bytes) - unchanged from R11:
//   0        Wfrag0  393216     1179648 hst0 262144    1703936  hout0 4194304
//   393216   Wfrag1  393216     1441792 hst1 262144    56229888 hout1 4194304
//   786432   Wi1frag 393216
//   5898240  xg0a 12582912   18481152 xg0b   31064064 xg1a   43646976 xg1b
//   total 60424192. hout1 last: absorbs last-step xg prefetch overrun.

#define SCH 32
#define NCH 32

typedef _Float16 half8 __attribute__((ext_vector_type(8)));
typedef _Float16 half4_t __attribute__((ext_vector_type(4)));
typedef float f32x4 __attribute__((ext_vector_type(4)));

__device__ __forceinline__ float rcp_(float x) {
#if __has_builtin(__builtin_amdgcn_rcpf)
    return __builtin_amdgcn_rcpf(x);
#else
    return 1.f / x;
#endif
}
__device__ __forceinline__ float exp2_(float x) {
#if __has_builtin(__builtin_amdgcn_exp2f)
    return __builtin_amdgcn_exp2f(x);
#else
    return exp2f(x);
#endif
}
__device__ __forceinline__ float sigf(float v) {
    return rcp_(1.f + exp2_(v * -1.442695041f));
}
__device__ __forceinline__ float tanh_(float v) {
    return 1.f - 2.f * rcp_(1.f + exp2_(v * 2.885390082f));
}

// ---------- prep: W -> MFMA B-fragment layout [kt][nt][lane][8] f16 ----------
__global__ __launch_bounds__(256) void prep_kernel(
    const float* __restrict__ Whh0, const float* __restrict__ Whh1,
    const float* __restrict__ Wih1,
    _Float16* __restrict__ Wfrag0, _Float16* __restrict__ Wfrag1,
    _Float16* __restrict__ Wi1frag) {
    int tid = blockIdx.x * 256 + threadIdx.x;     // 3 * 24576 = 73728
    int mat = tid / 24576;
    int r   = tid % 24576;                        // = (kt*48 + nt)*64 + lane
    int kt   = r / 3072;
    int rem  = r % 3072;
    int nt   = rem >> 6;
    int lane = rem & 63;
    int n = nt * 16 + (lane & 15);
    int k = kt * 32 + (lane >> 4) * 8;
    const float* src = (mat == 0 ? Whh0 : (mat == 1 ? Whh1 : Wih1)) + n * 256 + k;
    _Float16* dst = (mat == 0 ? Wfrag0 : (mat == 1 ? Wfrag1 : Wi1frag)) + (size_t)r * 8;
#pragma unroll
    for (int j = 0; j < 8; j++) dst[j] = (_Float16)src[j];
}

// ---------- fused pipeline kernel ----------
// blocks [0,32):   fat recurrence (waves 0-7: L0 chunk k; waves 8-15: L1 chunk k-2)
// blocks [32,64):  B0 producing xg0t for chunk k+1
// blocks [64,192): B1 producing xg1t for chunk k-1 (from hout of chunk k-1)
__global__
__attribute__((amdgpu_flat_work_group_size(1024, 1024), amdgpu_waves_per_eu(4, 4)))
void mega_kernel(
    const float* __restrict__ x, const float* __restrict__ meta,
    const float* __restrict__ Wih0, const float* __restrict__ bih0,
    const float* __restrict__ bhh0,
    const _Float16* __restrict__ Wfrag0, const _Float16* __restrict__ Wfrag1,
    const _Float16* __restrict__ Wi1frag,
    const float* __restrict__ bih1, const float* __restrict__ bhh1,
    float* __restrict__ hst0, float* __restrict__ hst1,
    _Float16* __restrict__ hout0, _Float16* __restrict__ hout1,
    _Float16* __restrict__ xg0a, _Float16* __restrict__ xg0b,
    _Float16* __restrict__ xg1a, _Float16* __restrict__ xg1b,
    const float* __restrict__ fcW, const float* __restrict__ fcb,
    float* __restrict__ out, int k) {
    __shared__ __align__(16) char smem[33792];
    __shared__ unsigned bar[2];
    const int bid = blockIdx.x;
    const int tid = threadIdx.x;

    if (bid < 32) {
        // ================= recurrence (two roles, decoupled) =================
        const int role = tid >> 9;             // 0: L0@k, 1: L1@k-2
        const int tid9 = tid & 511;
        const int lane = tid & 63;
        const int cc = role ? k - 2 : k;
        if (tid < 2) bar[tid] = 0;
        __syncthreads();                       // bar init visible to all waves
        if (cc < 0 || cc >= NCH) return;       // uniform per role (wave-uniform)

        const _Float16* Wfrag = role ? Wfrag1 : Wfrag0;
        const float* bhh      = role ? bhh1 : bhh0;
        const _Float16* xgt   = role ? ((cc & 1) ? xg1b : xg1a)
                                     : ((cc & 1) ? xg0b : xg0a);
        float* hstate         = role ? hst1 : hst0;
        _Float16* hof         = (cc & 1) ? hout1 : hout0;
        const bool doHout = (role == 0);
        const bool doFC   = (role == 1) && (cc == NCH - 1);

        _Float16* shA = (_Float16*)smem + role * 4096;  // 2 sides x 2048 halfs
        float* shred  = (float*)smem;          // FC alias (role0 retired at k=33)
        const int w = tid9 >> 6;
        const int lm = lane & 15;
        const int hi = lane >> 5;              // tp handled by this lane
        const int blk = bid;

        unsigned* bp = &bar[role];
        volatile unsigned* bpv = &bar[role];
        unsigned tgt = 8;

#define ROLE_BARRIER()                                                        \
        {                                                                     \
            __asm__ volatile("s_waitcnt lgkmcnt(0)" ::: "memory");            \
            if (lane == 0) atomicAdd(bp, 1u);                                 \
            while (*bpv < tgt) { }                                            \
            tgt += 8;                                                         \
            __asm__ volatile("" ::: "memory");                                \
        }

        int nt[6];
        nt[0] = 2 * w;      nt[1] = 2 * w + 1;
        nt[2] = 16 + 2 * w; nt[3] = 17 + 2 * w;
        nt[4] = 32 + 2 * w; nt[5] = 33 + 2 * w;

        half8 Bf[48];
#pragma unroll
        for (int kt = 0; kt < 8; kt++)
#pragma unroll
            for (int t = 0; t < 6; t++)
                Bf[kt * 6 + t] = *(const half8*)(Wfrag + (size_t)((kt * 48 + nt[t]) * 64 + lane) * 8);

        const float bbnA = bhh[512 + 32 * w + lm];
        const float bbnB = bhh[512 + 32 * w + 16 + lm];

        float hreg[4];                         // rows qh*4+r, col 32w+hi*16+lm
        if (cc == 0) {
#pragma unroll
            for (int r = 0; r < 4; r++) hreg[r] = 0.f;
        } else {
            f32x4 v0 = *(const f32x4*)(hstate + ((size_t)(blk * 8 + w) * 64 + lane) * 4);
#pragma unroll
            for (int r = 0; r < 4; r++) hreg[r] = v0[r];
        }

        const int rdo = (lane >> 4) * 64 + (lane & 7) * 8;
        const int wb2 = w * 256 + (hi * 2 + (lm >> 3)) * 64 + ((lane >> 4) & 1) * 32 + (lm & 7);

#pragma unroll
        for (int r = 0; r < 4; r++) shA[wb2 + r * 8] = (_Float16)hreg[r];

        // xg gate-major: row=(s*32+blk)*8+w, then [gate 3][slot 64][4]
        const _Float16* xp = xgt + (size_t)(blk * 8 + w) * 768 + lane * 4;
        // hout reg-native: [s][blk][w][lane][4]
        _Float16* hop = hof + (size_t)(blk * 8 + w) * 256 + lane * 4;

        half4_t xcb[2][3];
        xcb[0][0] = *(const half4_t*)(xp);
        xcb[0][1] = *(const half4_t*)(xp + 256);
        xcb[0][2] = *(const half4_t*)(xp + 512);
        xp += 196608;

        ROLE_BARRIER();

#define GRU_STEP(SIDE)                                                            \
    {                                                                             \
        xcb[(SIDE) ^ 1][0] = *(const half4_t*)(xp);                               \
        xcb[(SIDE) ^ 1][1] = *(const half4_t*)(xp + 256);                         \
        xcb[(SIDE) ^ 1][2] = *(const half4_t*)(xp + 512);                         \
        xp += 196608;                                                             \
        f32x4 acc[6];                                                             \
        acc[0] = acc[1] = acc[2] = acc[3] = (f32x4){0.f, 0.f, 0.f, 0.f};          \
        acc[4] = (f32x4){bbnA, bbnA, bbnA, bbnA};                                 \
        acc[5] = (f32x4){bbnB, bbnB, bbnB, bbnB};                                 \
        _Pragma("unroll")                                                         \
        for (int kt = 0; kt < 8; kt++) {                                          \
            half8 af = *(const half8*)(shA + (SIDE) * 2048 + kt * 256 + rdo);     \
            _Pragma("unroll")                                                     \
            for (int t = 0; t < 6; t++)                                           \
                acc[t] = __builtin_amdgcn_mfma_f32_16x16x32_f16(                  \
                    af, Bf[kt * 6 + t], acc[t], 0, 0, 0);                         \
        }                                                                         \
        f32x4 aR = hi ? acc[1] : acc[0];                                          \
        f32x4 aZ = hi ? acc[3] : acc[2];                                          \
        f32x4 aN = hi ? acc[5] : acc[4];                                          \
        half4_t xR = xcb[SIDE][0];                                                \
        half4_t xZ = xcb[SIDE][1];                                                \
        half4_t xN = xcb[SIDE][2];                                                \
        _Pragma("unroll")                                                         \
        for (int r = 0; r < 4; r++) {                                             \
            float rr = sigf((float)xR[r] + aR[r]);                                \
            float zz = sigf((float)xZ[r] + aZ[r]);                                \
            float nn = tanh_((float)xN[r] + rr * aN[r]);                          \
            hreg[r] = nn + zz * (hreg[r] - nn);                                   \
        }                                                                         \
        _Pragma("unroll")                                                         \
        for (int r = 0; r < 4; r++)                                               \
            shA[((SIDE) ^ 1) * 2048 + wb2 + r * 8] = (_Float16)hreg[r];           \
        if (doHout) {                                                             \
            half4_t hv;                                                           \
            _Pragma("unroll")                                                     \
            for (int r = 0; r < 4; r++) hv[r] = (_Float16)hreg[r];                \
            *(half4_t*)hop = hv;                                                  \
        }                                                                         \
        hop += 65536;                                                             \
        ROLE_BARRIER();                                                           \
    }

        for (int s2 = 0; s2 < SCH; s2 += 2) {
            GRU_STEP(0);
            GRU_STEP(1);
        }
#undef GRU_STEP

        {
            f32x4 v0;
#pragma unroll
            for (int r = 0; r < 4; r++) v0[r] = hreg[r];
            *(f32x4*)(hstate + ((size_t)(blk * 8 + w) * 64 + lane) * 4) = v0;
        }

        if (doFC) {
            float fw = fcW[32 * w + hi * 16 + lm];
            f32x4 pv;
#pragma unroll
            for (int r = 0; r < 4; r++) pv[r] = hreg[r] * fw;
            ROLE_BARRIER();
            *(f32x4*)(shred + (size_t)(w * 64 + lane) * 4) = pv;
            ROLE_BARRIER();
            if (tid9 < 8) {
                int qq = tid9 >> 2, rr2 = tid9 & 3;
                float a = fcb[0];
                for (int ww = 0; ww < 8; ww++)
                    for (int l2 = 0; l2 < 16; l2++)
                        a += shred[(ww * 64 + qq * 16 + l2) * 4 + rr2]
                           + shred[(ww * 64 + 32 + qq * 16 + l2) * 4 + rr2];
                out[blk * 8 + tid9] = a;
            }
        }
#undef ROLE_BARRIER
    } else if (bid < 64) {
        // ================= B0: xg0t(cb) = [x|meta] @ Wih0^T + bih0 (+bhh0 r,z) =================
        const int cb = k + 1;
        if (cb < 0 || cb >= NCH) return;
        _Float16* xg0 = (cb & 1) ? xg0b : xg0a;
        const int fb = bid - 32;                  // octet 0..31
        float* Wb = (float*)smem;                 // 6144 W + 768 bias
        for (int i = tid; i < 6912; i += 1024)
            Wb[i] = (i < 6144) ? Wih0[i]
                               : (bih0[i - 6144] + ((i - 6144) < 512 ? bhh0[i - 6144] : 0.f));
        __syncthreads();
        const int sub = tid >> 8;                 // step-quarter 0..3
        const int t = tid & 255;
        const int w = t >> 5, l32 = t & 31;
        const int qc = l32 >> 4, lm = l32 & 15;

        float Wr[6][8], br[6];
#pragma unroll
        for (int g3 = 0; g3 < 3; g3++)
#pragma unroll
            for (int tp = 0; tp < 2; tp++) {
                int n = g3 * 256 + 32 * w + 16 * tp + lm;
                int j6 = g3 * 2 + tp;
#pragma unroll
                for (int kk = 0; kk < 8; kk++) Wr[j6][kk] = Wb[n * 8 + kk];
                br[j6] = Wb[6144 + n];
            }
        const int b0 = fb * 8 + qc * 4;
        float4 mv[4];
#pragma unroll
        for (int r = 0; r < 4; r++) mv[r] = *(const float4*)(meta + (b0 + r) * 4);

        for (int sl = 0; sl < 8; sl++) {
            int s_local = sub * 8 + sl;
            int s = cb * SCH + s_local;
            float4 xv[4];
#pragma unroll
            for (int r = 0; r < 4; r++)
                xv[r] = *(const float4*)(x + ((size_t)(b0 + r) * 1024 + s) * 4);
            half4_t o[2][3];
#pragma unroll
            for (int g3 = 0; g3 < 3; g3++)
#pragma unroll
                for (int tp = 0; tp < 2; tp++) {
                    int j6 = g3 * 2 + tp;
#pragma unroll
                    for (int r = 0; r < 4; r++) {
                        float v = br[j6]
                            + xv[r].x * Wr[j6][0] + xv[r].y * Wr[j6][1]
                            + xv[r].z * Wr[j6][2] + xv[r].w * Wr[j6][3]
                            + mv[r].x * Wr[j6][4] + mv[r].y * Wr[j6][5]
                            + mv[r].z * Wr[j6][6] + mv[r].w * Wr[j6][7];
                        o[tp][g3][r] = (_Float16)v;
                    }
                }
            _Float16* dst = xg0 + ((size_t)(s_local * 32 + fb) * 8 + w) * 768;
#pragma unroll
            for (int tp = 0; tp < 2; tp++) {
                int slot4 = (l32 + tp * 32) * 4;
#pragma unroll
                for (int g3 = 0; g3 < 3; g3++)
                    *(half4_t*)(dst + g3 * 256 + slot4) = o[tp][g3];
            }
        }
    } else {
        // ================= B1: xg1t(c1) = h0(c1) @ Wih1^T + bih1 (+bhh1 r,z) =================
        const int c1 = k - 1;
        if (c1 < 0 || c1 >= NCH) return;
        const _Float16* hof = (c1 & 1) ? hout1 : hout0;
        _Float16* xg1 = (c1 & 1) ? xg1b : xg1a;
        const int fb = bid - 64;                  // 0..127
        const int s_ch = fb >> 2;                 // source step of hout
        const int bb8 = (fb & 3) * 8;             // base batch-octet (rows (fb&3)*64..)
        _Float16* Ah = (_Float16*)smem;           // [64 rows][264 cols] halfs (pad 8)

        // stage hout slab (64 rows x 256 cols) with transpose into LDS
#pragma unroll
        for (int i = 0; i < 4; i++) {
            int u = i * 1024 + tid;               // 4096 units = 16 row-quads x 256 cols
            int rq = u >> 8, c = u & 255;
            int blk8 = bb8 + (rq >> 1), qh = rq & 1;
            int wc = c >> 5, hic = (c >> 4) & 1, lmc = c & 15;
            half4_t hv = *(const half4_t*)(hof +
                (((size_t)(s_ch * 32 + blk8) * 8 + wc) * 64 + hic * 32 + qh * 16 + lmc) * 4);
#pragma unroll
            for (int r2 = 0; r2 < 4; r2++)
                Ah[(rq * 4 + r2) * 264 + c] = hv[r2];
        }
        __syncthreads();

        const int tloc = tid >> 8;                // m-tile within block 0..3
        const int t = tid & 255;
        const int wv = t >> 6, lane = t & 63;
        const int q = lane >> 4, lm = lane & 15;

        float bias[12];
#pragma unroll
        for (int j = 0; j < 12; j++) {
            int n = (wv * 12 + j) * 16 + lm;
            bias[j] = bih1[n] + (n < 512 ? bhh1[n] : 0.f);
        }
        const int tt = fb * 4 + tloc;             // global m-tile 0..511
        f32x4 acc[12] = {};
#pragma unroll
        for (int kt = 0; kt < 8; kt++) {
            half8 af = *(const half8*)(&Ah[(tloc * 16 + lm) * 264 + kt * 32 + q * 8]);
            half8 bf[12];
#pragma unroll
            for (int j = 0; j < 12; j++)
                bf[j] = *(const half8*)(Wi1frag + (size_t)((kt * 48 + wv * 12 + j) * 64 + lane) * 8);
#pragma unroll
            for (int j = 0; j < 12; j++)
                acc[j] = __builtin_amdgcn_mfma_f32_16x16x32_f16(af, bf[j], acc[j], 0, 0, 0);
        }
        const int s = tt >> 4, bt = tt & 15;
        const int blkw = bt * 2 + (q >> 1), qc2 = q & 1;
#pragma unroll
        for (int j = 0; j < 12; j++) {
            int n = (wv * 12 + j) * 16 + lm;
            int g3 = n >> 8, nn = n & 255;
            int wc2 = nn >> 5, tp = (nn >> 4) & 1, lmc2 = nn & 15;
            half4_t v;
#pragma unroll
            for (int r = 0; r < 4; r++) v[r] = (_Float16)(acc[j][r] + bias[j]);
            *(half4_t*)(xg1 + ((size_t)(s * 32 + blkw) * 8 + wc2) * 768
                             + g3 * 256 + (qc2 * 16 + lmc2 + tp * 32) * 4) = v;
        }
    }
}

extern "C" void kernel_launch(void* const* d_in, const int* in_sizes, int n_in,
                              void* d_out, int out_size, void* d_ws, size_t ws_size,
                              hipStream_t stream) {
    const float* x    = (const float*)d_in[0];
    const float* meta = (const float*)d_in[1];
    const float* Wih0 = (const float*)d_in[2];
    const float* Whh0 = (const float*)d_in[3];
    const float* bih0 = (const float*)d_in[4];
    const float* bhh0 = (const float*)d_in[5];
    const float* Wih1 = (const float*)d_in[6];
    const float* Whh1 = (const float*)d_in[7];
    const float* bih1 = (const float*)d_in[8];
    const float* bhh1 = (const float*)d_in[9];
    const float* fcW  = (const float*)d_in[10];
    const float* fcb  = (const float*)d_in[11];
    float* out = (float*)d_out;

    char* ws = (char*)d_ws;
    _Float16* Wfrag0  = (_Float16*)(ws + 0);
    _Float16* Wfrag1  = (_Float16*)(ws + 393216);
    _Float16* Wi1frag = (_Float16*)(ws + 786432);
    float*    hst0    = (float*)(ws + 1179648);
    float*    hst1    = (float*)(ws + 1441792);
    _Float16* hout0   = (_Float16*)(ws + 1703936);
    _Float16* xg0a    = (_Float16*)(ws + 5898240);
    _Float16* xg0b    = (_Float16*)(ws + 18481152);
    _Float16* xg1a    = (_Float16*)(ws + 31064064);
    _Float16* xg1b    = (_Float16*)(ws + 43646976);
    _Float16* hout1   = (_Float16*)(ws + 56229888);

    prep_kernel<<<288, 256, 0, stream>>>(Whh0, Whh1, Wih1, Wfrag0, Wfrag1, Wi1frag);

    for (int k = -1; k <= NCH + 1; k++) {
        mega_kernel<<<192, 1024, 0, stream>>>(
            x, meta, Wih0, bih0, bhh0, Wfrag0, Wfrag1, Wi1frag, bih1, bhh1,
            hst0, hst1, hout0, hout1, xg0a, xg0b, xg1a, xg1b, fcW, fcb, out, k);
    }
}

// Round 4
// 2870.183 us; speedup vs baseline: 5.4063x; 5.4063x over previous
//
#include <hip/hip_runtime.h>
#include <hip/hip_fp16.h>

// GRUPK R14 = R13 resubmit (R3 bench was an infra failure: container died twice;
// no kernel-level signal). See R13 notes below.
//
// GRUPK R13: R11 structure + split MFMA chains + reg-direct hout.
// R12 post-mortem: fat block (4 waves/SIMD) capped regs at 128/wave -> Bf[48]
// (192 VGPR) spilled to scratch (VGPR 64, FETCH +45MB, WRITE +31MB, 15.5ms).
// Co-resident-roles idea is architecturally dead at this tile shape. Reverted.
// R13 vs R11:
// (1) acc chains split 8-deep -> 2x4-deep (aA kt0-3, aB kt4-7, summed at end):
//     12 independent MFMA chains/wave instead of 6; halves dependent-latency
//     exposure in the serial step path. +24 AGPR, +12 v_add/step.
// (2) hout stored directly from hreg (half4/lane, coalesced) - removes the
//     shA-read -> lgkmcnt -> global_store tail from role0's step.
// (3) B1 stages its 64x256 hout slab into LDS ([64][264] pad) and feeds MFMA
//     A-fragments from there (R12's staging, ported to 512 threads; verified
//     index math).
//
// ws layout (bytes) - unchanged from R11:
//   0        Wfrag0  393216     1179648 hst0 262144    1703936  hout0 4194304
//   393216   Wfrag1  393216     1441792 hst1 262144    56229888 hout1 4194304
//   786432   Wi1frag 393216
//   5898240  xg0a 12582912   18481152 xg0b   31064064 xg1a   43646976 xg1b
//   total 60424192. hout1 last: absorbs last-step xg prefetch overrun.

#define SCH 32
#define NCH 32

typedef _Float16 half8 __attribute__((ext_vector_type(8)));
typedef _Float16 half4_t __attribute__((ext_vector_type(4)));
typedef float f32x4 __attribute__((ext_vector_type(4)));

__device__ __forceinline__ float rcp_(float x) {
#if __has_builtin(__builtin_amdgcn_rcpf)
    return __builtin_amdgcn_rcpf(x);
#else
    return 1.f / x;
#endif
}
__device__ __forceinline__ float exp2_(float x) {
#if __has_builtin(__builtin_amdgcn_exp2f)
    return __builtin_amdgcn_exp2f(x);
#else
    return exp2f(x);
#endif
}
__device__ __forceinline__ float sigf(float v) {
    return rcp_(1.f + exp2_(v * -1.442695041f));
}
__device__ __forceinline__ float tanh_(float v) {
    return 1.f - 2.f * rcp_(1.f + exp2_(v * 2.885390082f));
}

// LDS-only barrier: drains DS ops, leaves vmcnt (global loads/stores) in flight.
__device__ __forceinline__ void lds_barrier() {
    __asm__ volatile("s_waitcnt lgkmcnt(0)" ::: "memory");
    __builtin_amdgcn_s_barrier();
}

// ---------- prep: W -> MFMA B-fragment layout [kt][nt][lane][8] f16 ----------
__global__ __launch_bounds__(256) void prep_kernel(
    const float* __restrict__ Whh0, const float* __restrict__ Whh1,
    const float* __restrict__ Wih1,
    _Float16* __restrict__ Wfrag0, _Float16* __restrict__ Wfrag1,
    _Float16* __restrict__ Wi1frag) {
    int tid = blockIdx.x * 256 + threadIdx.x;     // 3 * 24576 = 73728
    int mat = tid / 24576;
    int r   = tid % 24576;                        // = (kt*48 + nt)*64 + lane
    int kt   = r / 3072;
    int rem  = r % 3072;
    int nt   = rem >> 6;
    int lane = rem & 63;
    int n = nt * 16 + (lane & 15);
    int k = kt * 32 + (lane >> 4) * 8;
    const float* src = (mat == 0 ? Whh0 : (mat == 1 ? Whh1 : Wih1)) + n * 256 + k;
    _Float16* dst = (mat == 0 ? Wfrag0 : (mat == 1 ? Wfrag1 : Wi1frag)) + (size_t)r * 8;
#pragma unroll
    for (int j = 0; j < 8; j++) dst[j] = (_Float16)src[j];
}

// ---------- fused pipeline kernel ----------
// blocks [0,64):   recurrence (role0 = L0 chunk k, role1 = L1 chunk k-2)
// blocks [64,96):  B0 producing xg0t for chunk k+1
// blocks [96,224): B1 producing xg1t for chunk k-1 (from hout of chunk k-1)
__global__
__attribute__((amdgpu_flat_work_group_size(512, 512), amdgpu_waves_per_eu(2, 2)))
void mega_kernel(
    const float* __restrict__ x, const float* __restrict__ meta,
    const float* __restrict__ Wih0, const float* __restrict__ bih0,
    const float* __restrict__ bhh0,
    const _Float16* __restrict__ Wfrag0, const _Float16* __restrict__ Wfrag1,
    const _Float16* __restrict__ Wi1frag,
    const float* __restrict__ bih1, const float* __restrict__ bhh1,
    float* __restrict__ hst0, float* __restrict__ hst1,
    _Float16* __restrict__ hout0, _Float16* __restrict__ hout1,
    _Float16* __restrict__ xg0a, _Float16* __restrict__ xg0b,
    _Float16* __restrict__ xg1a, _Float16* __restrict__ xg1b,
    const float* __restrict__ fcW, const float* __restrict__ fcb,
    float* __restrict__ out, int k) {
    __shared__ __align__(16) char smem[33792];
    const int bid = blockIdx.x;
    const int tid = threadIdx.x;

    if (bid < 64) {
        // ================= recurrence =================
        const int role = bid >> 5;
        const int cc = role ? k - 2 : k;
        if (cc < 0 || cc >= NCH) return;
        const _Float16* Wfrag = role ? Wfrag1 : Wfrag0;
        const float* bhh      = role ? bhh1 : bhh0;
        const _Float16* xgt   = role ? ((cc & 1) ? xg1b : xg1a)
                                     : ((cc & 1) ? xg0b : xg0a);
        float* hstate         = role ? hst1 : hst0;
        _Float16* hof         = (cc & 1) ? hout1 : hout0;
        const bool doHout = (role == 0);
        const bool doFC   = (role == 1) && (cc == NCH - 1);

        _Float16* shA = (_Float16*)smem;   // 2 sides x [kt 8][kq 4][row 8][off 8] = 2x2048 halfs
        float* shred  = (float*)smem;      // FC alias (post-loop only)
        const int w = tid >> 6, lane = tid & 63;
        const int lm = lane & 15;
        const int hi = lane >> 5;          // tp handled by this lane
        const int blk = bid & 31;

        int nt[6];
        nt[0] = 2 * w;      nt[1] = 2 * w + 1;
        nt[2] = 16 + 2 * w; nt[3] = 17 + 2 * w;
        nt[4] = 32 + 2 * w; nt[5] = 33 + 2 * w;

        half8 Bf[48];
#pragma unroll
        for (int kt = 0; kt < 8; kt++)
#pragma unroll
            for (int t = 0; t < 6; t++)
                Bf[kt * 6 + t] = *(const half8*)(Wfrag + (size_t)((kt * 48 + nt[t]) * 64 + lane) * 8);

        const float bbnA = bhh[512 + 32 * w + lm];
        const float bbnB = bhh[512 + 32 * w + 16 + lm];

        float hreg[4];                     // rows qh*4+r, col 32w+hi*16+lm
        if (cc == 0) {
#pragma unroll
            for (int r = 0; r < 4; r++) hreg[r] = 0.f;
        } else {
            f32x4 v0 = *(const f32x4*)(hstate + ((size_t)(blk * 8 + w) * 64 + lane) * 4);
#pragma unroll
            for (int r = 0; r < 4; r++) hreg[r] = v0[r];
        }

        const int rdo = (lane >> 4) * 64 + (lane & 7) * 8;
        const int wb2 = w * 256 + (hi * 2 + (lm >> 3)) * 64 + ((lane >> 4) & 1) * 32 + (lm & 7);

#pragma unroll
        for (int r = 0; r < 4; r++) shA[wb2 + r * 8] = (_Float16)hreg[r];

        // xg gate-major: row=(s*32+blk)*8+w, then [gate 3][slot 64][4]
        const _Float16* xp = xgt + (size_t)(blk * 8 + w) * 768 + lane * 4;
        // hout reg-native: [s][blk][w][lane][4]
        _Float16* hop = hof + (size_t)(blk * 8 + w) * 256 + lane * 4;

        half4_t xcb[2][3];
        xcb[0][0] = *(const half4_t*)(xp);
        xcb[0][1] = *(const half4_t*)(xp + 256);
        xcb[0][2] = *(const half4_t*)(xp + 512);
        xp += 196608;

        __syncthreads();

#define GRU_STEP(SIDE)                                                            \
    {                                                                             \
        xcb[(SIDE) ^ 1][0] = *(const half4_t*)(xp);                               \
        xcb[(SIDE) ^ 1][1] = *(const half4_t*)(xp + 256);                         \
        xcb[(SIDE) ^ 1][2] = *(const half4_t*)(xp + 512);                         \
        xp += 196608;                                                             \
        f32x4 aA[6], aB[6];                                                       \
        aA[0] = aA[1] = aA[2] = aA[3] = (f32x4){0.f, 0.f, 0.f, 0.f};              \
        aA[4] = (f32x4){bbnA, bbnA, bbnA, bbnA};                                  \
        aA[5] = (f32x4){bbnB, bbnB, bbnB, bbnB};                                  \
        aB[0] = aB[1] = aB[2] = aB[3] = (f32x4){0.f, 0.f, 0.f, 0.f};              \
        aB[4] = aB[5] = (f32x4){0.f, 0.f, 0.f, 0.f};                              \
        _Pragma("unroll")                                                         \
        for (int kt = 0; kt < 4; kt++) {                                          \
            half8 af = *(const half8*)(shA + (SIDE) * 2048 + kt * 256 + rdo);     \
            _Pragma("unroll")                                                     \
            for (int t = 0; t < 6; t++)                                           \
                aA[t] = __builtin_amdgcn_mfma_f32_16x16x32_f16(                   \
                    af, Bf[kt * 6 + t], aA[t], 0, 0, 0);                          \
        }                                                                         \
        _Pragma("unroll")                                                         \
        for (int kt = 4; kt < 8; kt++) {                                          \
            half8 af = *(const half8*)(shA + (SIDE) * 2048 + kt * 256 + rdo);     \
            _Pragma("unroll")                                                     \
            for (int t = 0; t < 6; t++)                                           \
                aB[t] = __builtin_amdgcn_mfma_f32_16x16x32_f16(                   \
                    af, Bf[kt * 6 + t], aB[t], 0, 0, 0);                          \
        }                                                                         \
        f32x4 aR = (hi ? aA[1] : aA[0]) + (hi ? aB[1] : aB[0]);                   \
        f32x4 aZ = (hi ? aA[3] : aA[2]) + (hi ? aB[3] : aB[2]);                   \
        f32x4 aN = (hi ? aA[5] : aA[4]) + (hi ? aB[5] : aB[4]);                   \
        half4_t xR = xcb[SIDE][0];                                                \
        half4_t xZ = xcb[SIDE][1];                                                \
        half4_t xN = xcb[SIDE][2];                                                \
        _Pragma("unroll")                                                         \
        for (int r = 0; r < 4; r++) {                                             \
            float rr = sigf((float)xR[r] + aR[r]);                                \
            float zz = sigf((float)xZ[r] + aZ[r]);                                \
            float nn = tanh_((float)xN[r] + rr * aN[r]);                          \
            hreg[r] = nn + zz * (hreg[r] - nn);                                   \
        }                                                                         \
        _Pragma("unroll")                                                         \
        for (int r = 0; r < 4; r++)                                               \
            shA[((SIDE) ^ 1) * 2048 + wb2 + r * 8] = (_Float16)hreg[r];           \
        if (doHout) {                                                             \
            half4_t hv;                                                           \
            _Pragma("unroll")                                                     \
            for (int r = 0; r < 4; r++) hv[r] = (_Float16)hreg[r];                \
            *(half4_t*)hop = hv;                                                  \
        }                                                                         \
        hop += 65536;                                                             \
        lds_barrier();                                                            \
    }

        for (int s2 = 0; s2 < SCH; s2 += 2) {
            GRU_STEP(0);
            GRU_STEP(1);
        }
#undef GRU_STEP

        {
            f32x4 v0;
#pragma unroll
            for (int r = 0; r < 4; r++) v0[r] = hreg[r];
            *(f32x4*)(hstate + ((size_t)(blk * 8 + w) * 64 + lane) * 4) = v0;
        }

        if (doFC) {
            float fw = fcW[32 * w + hi * 16 + lm];
            f32x4 pv;
#pragma unroll
            for (int r = 0; r < 4; r++) pv[r] = hreg[r] * fw;
            __syncthreads();   // shA reads done before shred alias write
            *(f32x4*)(shred + (size_t)(w * 64 + lane) * 4) = pv;
            __syncthreads();
            if (tid < 8) {
                int qq = tid >> 2, rr2 = tid & 3;
                float a = fcb[0];
                for (int ww = 0; ww < 8; ww++)
                    for (int l2 = 0; l2 < 16; l2++)
                        a += shred[(ww * 64 + qq * 16 + l2) * 4 + rr2]
                           + shred[(ww * 64 + 32 + qq * 16 + l2) * 4 + rr2];
                out[blk * 8 + tid] = a;
            }
        }
    } else if (bid < 96) {
        // ================= B0: xg0t(cb) = [x|meta] @ Wih0^T + bih0 (+bhh0 r,z) =================
        const int cb = k + 1;
        if (cb < 0 || cb >= NCH) return;
        _Float16* xg0 = (cb & 1) ? xg0b : xg0a;
        const int fb = bid - 64;                  // octet 0..31
        float* Wb = (float*)smem;                 // 6144 W + 768 bias
        for (int i = tid; i < 6912; i += 512)
            Wb[i] = (i < 6144) ? Wih0[i]
                               : (bih0[i - 6144] + ((i - 6144) < 512 ? bhh0[i - 6144] : 0.f));
        __syncthreads();
        const int sub = tid >> 8;                 // step-half 0..1
        const int t = tid & 255;
        const int w = t >> 5, l32 = t & 31;
        const int qc = l32 >> 4, lm = l32 & 15;

        float Wr[6][8], br[6];
#pragma unroll
        for (int g3 = 0; g3 < 3; g3++)
#pragma unroll
            for (int tp = 0; tp < 2; tp++) {
                int n = g3 * 256 + 32 * w + 16 * tp + lm;
                int j6 = g3 * 2 + tp;
#pragma unroll
                for (int kk = 0; kk < 8; kk++) Wr[j6][kk] = Wb[n * 8 + kk];
                br[j6] = Wb[6144 + n];
            }
        const int b0 = fb * 8 + qc * 4;
        float4 mv[4];
#pragma unroll
        for (int r = 0; r < 4; r++) mv[r] = *(const float4*)(meta + (b0 + r) * 4);

        for (int sl = 0; sl < 16; sl++) {
            int s_local = sub * 16 + sl;
            int s = cb * SCH + s_local;
            float4 xv[4];
#pragma unroll
            for (int r = 0; r < 4; r++)
                xv[r] = *(const float4*)(x + ((size_t)(b0 + r) * 1024 + s) * 4);
            half4_t o[2][3];
#pragma unroll
            for (int g3 = 0; g3 < 3; g3++)
#pragma unroll
                for (int tp = 0; tp < 2; tp++) {
                    int j6 = g3 * 2 + tp;
#pragma unroll
                    for (int r = 0; r < 4; r++) {
                        float v = br[j6]
                            + xv[r].x * Wr[j6][0] + xv[r].y * Wr[j6][1]
                            + xv[r].z * Wr[j6][2] + xv[r].w * Wr[j6][3]
                            + mv[r].x * Wr[j6][4] + mv[r].y * Wr[j6][5]
                            + mv[r].z * Wr[j6][6] + mv[r].w * Wr[j6][7];
                        o[tp][g3][r] = (_Float16)v;
                    }
                }
            _Float16* dst = xg0 + ((size_t)(s_local * 32 + fb) * 8 + w) * 768;
#pragma unroll
            for (int tp = 0; tp < 2; tp++) {
                int slot4 = (l32 + tp * 32) * 4;
#pragma unroll
                for (int g3 = 0; g3 < 3; g3++)
                    *(half4_t*)(dst + g3 * 256 + slot4) = o[tp][g3];
            }
        }
    } else {
        // ================= B1: xg1t(c1) = h0(c1) @ Wih1^T + bih1 (+bhh1 r,z) =================
        const int c1 = k - 1;
        if (c1 < 0 || c1 >= NCH) return;
        const _Float16* hof = (c1 & 1) ? hout1 : hout0;
        _Float16* xg1 = (c1 & 1) ? xg1b : xg1a;
        const int fb = bid - 96;                  // 0..127
        const int s_ch = fb >> 2;                 // source step of hout
        const int bb8 = (fb & 3) * 8;             // base batch-octet
        _Float16* Ah = (_Float16*)smem;           // [64 rows][264 cols] halfs (pad 8)

        // stage hout slab (64 batch rows x 256 cols) with transpose into LDS
#pragma unroll
        for (int i = 0; i < 8; i++) {
            int u = i * 512 + tid;                // 4096 units = 16 row-quads x 256 cols
            int rq = u >> 8, c = u & 255;
            int blk8 = bb8 + (rq >> 1), qh = rq & 1;
            int wc = c >> 5, hic = (c >> 4) & 1, lmc = c & 15;
            half4_t hv = *(const half4_t*)(hof +
                (((size_t)(s_ch * 32 + blk8) * 8 + wc) * 64 + hic * 32 + qh * 16 + lmc) * 4);
#pragma unroll
            for (int r2 = 0; r2 < 4; r2++)
                Ah[(rq * 4 + r2) * 264 + c] = hv[r2];
        }
        __syncthreads();

        const int th = tid >> 8;                  // m-tile pair 0..1
        const int t = tid & 255;
        const int wv = t >> 6, lane = t & 63;
        const int q = lane >> 4, lm = lane & 15;

        float bias[12];
#pragma unroll
        for (int j = 0; j < 12; j++) {
            int n = (wv * 12 + j) * 16 + lm;
            bias[j] = bih1[n] + (n < 512 ? bhh1[n] : 0.f);
        }
        f32x4 acc[2][12] = {};
#pragma unroll
        for (int kt = 0; kt < 8; kt++) {
            half8 af[2], bf[12];
#pragma unroll
            for (int i = 0; i < 2; i++)
                af[i] = *(const half8*)(&Ah[((th * 2 + i) * 16 + lm) * 264 + kt * 32 + q * 8]);
#pragma unroll
            for (int j = 0; j < 12; j++)
                bf[j] = *(const half8*)(Wi1frag + (size_t)((kt * 48 + wv * 12 + j) * 64 + lane) * 8);
#pragma unroll
            for (int i = 0; i < 2; i++)
#pragma unroll
                for (int j = 0; j < 12; j++)
                    acc[i][j] = __builtin_amdgcn_mfma_f32_16x16x32_f16(af[i], bf[j], acc[i][j], 0, 0, 0);
        }
#pragma unroll
        for (int i = 0; i < 2; i++) {
            int tt = fb * 4 + th * 2 + i, s = tt >> 4, bt = tt & 15;
            int blkw = bt * 2 + (q >> 1), qc2 = q & 1;
#pragma unroll
            for (int j = 0; j < 12; j++) {
                int n = (wv * 12 + j) * 16 + lm;
                int g3 = n >> 8, nn = n & 255;
                int wc2 = nn >> 5, tp = (nn >> 4) & 1, lmc2 = nn & 15;
                half4_t v;
#pragma unroll
                for (int r = 0; r < 4; r++) v[r] = (_Float16)(acc[i][j][r] + bias[j]);
                *(half4_t*)(xg1 + ((size_t)(s * 32 + blkw) * 8 + wc2) * 768
                                 + g3 * 256 + (qc2 * 16 + lmc2 + tp * 32) * 4) = v;
            }
        }
    }
}

extern "C" void kernel_launch(void* const* d_in, const int* in_sizes, int n_in,
                              void* d_out, int out_size, void* d_ws, size_t ws_size,
                              hipStream_t stream) {
    const float* x    = (const float*)d_in[0];
    const float* meta = (const float*)d_in[1];
    const float* Wih0 = (const float*)d_in[2];
    const float* Whh0 = (const float*)d_in[3];
    const float* bih0 = (const float*)d_in[4];
    const float* bhh0 = (const float*)d_in[5];
    const float* Wih1 = (const float*)d_in[6];
    const float* Whh1 = (const float*)d_in[7];
    const float* bih1 = (const float*)d_in[8];
    const float* bhh1 = (const float*)d_in[9];
    const float* fcW  = (const float*)d_in[10];
    const float* fcb  = (const float*)d_in[11];
    float* out = (float*)d_out;

    char* ws = (char*)d_ws;
    _Float16* Wfrag0  = (_Float16*)(ws + 0);
    _Float16* Wfrag1  = (_Float16*)(ws + 393216);
    _Float16* Wi1frag = (_Float16*)(ws + 786432);
    float*    hst0    = (float*)(ws + 1179648);
    float*    hst1    = (float*)(ws + 1441792);
    _Float16* hout0   = (_Float16*)(ws + 1703936);
    _Float16* xg0a    = (_Float16*)(ws + 5898240);
    _Float16* xg0b    = (_Float16*)(ws + 18481152);
    _Float16* xg1a    = (_Float16*)(ws + 31064064);
    _Float16* xg1b    = (_Float16*)(ws + 43646976);
    _Float16* hout1   = (_Float16*)(ws + 56229888);

    prep_kernel<<<288, 256, 0, stream>>>(Whh0, Whh1, Wih1, Wfrag0, Wfrag1, Wi1frag);

    for (int k = -1; k <= NCH + 1; k++) {
        mega_kernel<<<224, 512, 0, stream>>>(
            x, meta, Wih0, bih0, bhh0, Wfrag0, Wfrag1, Wi1frag, bih1, bhh1,
            hst0, hst1, hout0, hout1, xg0a, xg0b, xg1a, xg1b, fcW, fcb, out, k);
    }
}

// Round 5
// 1490.258 us; speedup vs baseline: 10.4123x; 1.9260x over previous
//
#include <hip/hip_runtime.h>
#include <hip/hip_fp16.h>

// GRUPK R15: R11 MFMA structure (single 8-deep chains) + reg-direct hout + B1
// LDS-staged transpose.
// R14 post-mortem: chain split (+24 acc regs) pushed the recur wave past the
// 256-reg/wave cliff at waves_per_eu(2,2) -> inner-loop spills (FETCH +1.5MB,
// WRITE +2.4MB, dur 49->87us). Register budget rule: recur wave has ~6 spare
// regs; Bf[48]=192 + acc[6]=24 + xcb/hreg/addr ~= 250/256.
// R15 = R14 minus the chain split (acc[6] restored), keeping:
// (1) hout stored directly from hreg (half4/lane, coalesced) - removes the
//     shA-read -> lgkmcnt -> global_store tail from role0's step.
// (2) B1 stages its 64x256 hout slab into LDS ([64][264] pad) and feeds MFMA
//     A-fragments from there.
//
// ws layout (bytes) - unchanged from R11:
//   0        Wfrag0  393216     1179648 hst0 262144    1703936  hout0 4194304
//   393216   Wfrag1  393216     1441792 hst1 262144    56229888 hout1 4194304
//   786432   Wi1frag 393216
//   5898240  xg0a 12582912   18481152 xg0b   31064064 xg1a   43646976 xg1b
//   total 60424192. hout1 last: absorbs last-step xg prefetch overrun.

#define SCH 32
#define NCH 32

typedef _Float16 half8 __attribute__((ext_vector_type(8)));
typedef _Float16 half4_t __attribute__((ext_vector_type(4)));
typedef float f32x4 __attribute__((ext_vector_type(4)));

__device__ __forceinline__ float rcp_(float x) {
#if __has_builtin(__builtin_amdgcn_rcpf)
    return __builtin_amdgcn_rcpf(x);
#else
    return 1.f / x;
#endif
}
__device__ __forceinline__ float exp2_(float x) {
#if __has_builtin(__builtin_amdgcn_exp2f)
    return __builtin_amdgcn_exp2f(x);
#else
    return exp2f(x);
#endif
}
__device__ __forceinline__ float sigf(float v) {
    return rcp_(1.f + exp2_(v * -1.442695041f));
}
__device__ __forceinline__ float tanh_(float v) {
    return 1.f - 2.f * rcp_(1.f + exp2_(v * 2.885390082f));
}

// LDS-only barrier: drains DS ops, leaves vmcnt (global loads/stores) in flight.
__device__ __forceinline__ void lds_barrier() {
    __asm__ volatile("s_waitcnt lgkmcnt(0)" ::: "memory");
    __builtin_amdgcn_s_barrier();
}

// ---------- prep: W -> MFMA B-fragment layout [kt][nt][lane][8] f16 ----------
__global__ __launch_bounds__(256) void prep_kernel(
    const float* __restrict__ Whh0, const float* __restrict__ Whh1,
    const float* __restrict__ Wih1,
    _Float16* __restrict__ Wfrag0, _Float16* __restrict__ Wfrag1,
    _Float16* __restrict__ Wi1frag) {
    int tid = blockIdx.x * 256 + threadIdx.x;     // 3 * 24576 = 73728
    int mat = tid / 24576;
    int r   = tid % 24576;                        // = (kt*48 + nt)*64 + lane
    int kt   = r / 3072;
    int rem  = r % 3072;
    int nt   = rem >> 6;
    int lane = rem & 63;
    int n = nt * 16 + (lane & 15);
    int k = kt * 32 + (lane >> 4) * 8;
    const float* src = (mat == 0 ? Whh0 : (mat == 1 ? Whh1 : Wih1)) + n * 256 + k;
    _Float16* dst = (mat == 0 ? Wfrag0 : (mat == 1 ? Wfrag1 : Wi1frag)) + (size_t)r * 8;
#pragma unroll
    for (int j = 0; j < 8; j++) dst[j] = (_Float16)src[j];
}

// ---------- fused pipeline kernel ----------
// blocks [0,64):   recurrence (role0 = L0 chunk k, role1 = L1 chunk k-2)
// blocks [64,96):  B0 producing xg0t for chunk k+1
// blocks [96,224): B1 producing xg1t for chunk k-1 (from hout of chunk k-1)
__global__
__attribute__((amdgpu_flat_work_group_size(512, 512), amdgpu_waves_per_eu(2, 2)))
void mega_kernel(
    const float* __restrict__ x, const float* __restrict__ meta,
    const float* __restrict__ Wih0, const float* __restrict__ bih0,
    const float* __restrict__ bhh0,
    const _Float16* __restrict__ Wfrag0, const _Float16* __restrict__ Wfrag1,
    const _Float16* __restrict__ Wi1frag,
    const float* __restrict__ bih1, const float* __restrict__ bhh1,
    float* __restrict__ hst0, float* __restrict__ hst1,
    _Float16* __restrict__ hout0, _Float16* __restrict__ hout1,
    _Float16* __restrict__ xg0a, _Float16* __restrict__ xg0b,
    _Float16* __restrict__ xg1a, _Float16* __restrict__ xg1b,
    const float* __restrict__ fcW, const float* __restrict__ fcb,
    float* __restrict__ out, int k) {
    __shared__ __align__(16) char smem[33792];
    const int bid = blockIdx.x;
    const int tid = threadIdx.x;

    if (bid < 64) {
        // ================= recurrence =================
        const int role = bid >> 5;
        const int cc = role ? k - 2 : k;
        if (cc < 0 || cc >= NCH) return;
        const _Float16* Wfrag = role ? Wfrag1 : Wfrag0;
        const float* bhh      = role ? bhh1 : bhh0;
        const _Float16* xgt   = role ? ((cc & 1) ? xg1b : xg1a)
                                     : ((cc & 1) ? xg0b : xg0a);
        float* hstate         = role ? hst1 : hst0;
        _Float16* hof         = (cc & 1) ? hout1 : hout0;
        const bool doHout = (role == 0);
        const bool doFC   = (role == 1) && (cc == NCH - 1);

        _Float16* shA = (_Float16*)smem;   // 2 sides x [kt 8][kq 4][row 8][off 8] = 2x2048 halfs
        float* shred  = (float*)smem;      // FC alias (post-loop only)
        const int w = tid >> 6, lane = tid & 63;
        const int lm = lane & 15;
        const int hi = lane >> 5;          // tp handled by this lane
        const int blk = bid & 31;

        int nt[6];
        nt[0] = 2 * w;      nt[1] = 2 * w + 1;
        nt[2] = 16 + 2 * w; nt[3] = 17 + 2 * w;
        nt[4] = 32 + 2 * w; nt[5] = 33 + 2 * w;

        half8 Bf[48];
#pragma unroll
        for (int kt = 0; kt < 8; kt++)
#pragma unroll
            for (int t = 0; t < 6; t++)
                Bf[kt * 6 + t] = *(const half8*)(Wfrag + (size_t)((kt * 48 + nt[t]) * 64 + lane) * 8);

        const float bbnA = bhh[512 + 32 * w + lm];
        const float bbnB = bhh[512 + 32 * w + 16 + lm];

        float hreg[4];                     // rows qh*4+r, col 32w+hi*16+lm
        if (cc == 0) {
#pragma unroll
            for (int r = 0; r < 4; r++) hreg[r] = 0.f;
        } else {
            f32x4 v0 = *(const f32x4*)(hstate + ((size_t)(blk * 8 + w) * 64 + lane) * 4);
#pragma unroll
            for (int r = 0; r < 4; r++) hreg[r] = v0[r];
        }

        const int rdo = (lane >> 4) * 64 + (lane & 7) * 8;
        const int wb2 = w * 256 + (hi * 2 + (lm >> 3)) * 64 + ((lane >> 4) & 1) * 32 + (lm & 7);

#pragma unroll
        for (int r = 0; r < 4; r++) shA[wb2 + r * 8] = (_Float16)hreg[r];

        // xg gate-major: row=(s*32+blk)*8+w, then [gate 3][slot 64][4]
        const _Float16* xp = xgt + (size_t)(blk * 8 + w) * 768 + lane * 4;
        // hout reg-native: [s][blk][w][lane][4]
        _Float16* hop = hof + (size_t)(blk * 8 + w) * 256 + lane * 4;

        half4_t xcb[2][3];
        xcb[0][0] = *(const half4_t*)(xp);
        xcb[0][1] = *(const half4_t*)(xp + 256);
        xcb[0][2] = *(const half4_t*)(xp + 512);
        xp += 196608;

        __syncthreads();

#define GRU_STEP(SIDE)                                                            \
    {                                                                             \
        xcb[(SIDE) ^ 1][0] = *(const half4_t*)(xp);                               \
        xcb[(SIDE) ^ 1][1] = *(const half4_t*)(xp + 256);                         \
        xcb[(SIDE) ^ 1][2] = *(const half4_t*)(xp + 512);                         \
        xp += 196608;                                                             \
        f32x4 acc[6];                                                             \
        acc[0] = acc[1] = acc[2] = acc[3] = (f32x4){0.f, 0.f, 0.f, 0.f};          \
        acc[4] = (f32x4){bbnA, bbnA, bbnA, bbnA};                                 \
        acc[5] = (f32x4){bbnB, bbnB, bbnB, bbnB};                                 \
        _Pragma("unroll")                                                         \
        for (int kt = 0; kt < 8; kt++) {                                          \
            half8 af = *(const half8*)(shA + (SIDE) * 2048 + kt * 256 + rdo);     \
            _Pragma("unroll")                                                     \
            for (int t = 0; t < 6; t++)                                           \
                acc[t] = __builtin_amdgcn_mfma_f32_16x16x32_f16(                  \
                    af, Bf[kt * 6 + t], acc[t], 0, 0, 0);                         \
        }                                                                         \
        f32x4 aR = hi ? acc[1] : acc[0];                                          \
        f32x4 aZ = hi ? acc[3] : acc[2];                                          \
        f32x4 aN = hi ? acc[5] : acc[4];                                          \
        half4_t xR = xcb[SIDE][0];                                                \
        half4_t xZ = xcb[SIDE][1];                                                \
        half4_t xN = xcb[SIDE][2];                                                \
        _Pragma("unroll")                                                         \
        for (int r = 0; r < 4; r++) {                                             \
            float rr = sigf((float)xR[r] + aR[r]);                                \
            float zz = sigf((float)xZ[r] + aZ[r]);                                \
            float nn = tanh_((float)xN[r] + rr * aN[r]);                          \
            hreg[r] = nn + zz * (hreg[r] - nn);                                   \
        }                                                                         \
        _Pragma("unroll")                                                         \
        for (int r = 0; r < 4; r++)                                               \
            shA[((SIDE) ^ 1) * 2048 + wb2 + r * 8] = (_Float16)hreg[r];           \
        if (doHout) {                                                             \
            half4_t hv;                                                           \
            _Pragma("unroll")                                                     \
            for (int r = 0; r < 4; r++) hv[r] = (_Float16)hreg[r];                \
            *(half4_t*)hop = hv;                                                  \
        }                                                                         \
        hop += 65536;                                                             \
        lds_barrier();                                                            \
    }

        for (int s2 = 0; s2 < SCH; s2 += 2) {
            GRU_STEP(0);
            GRU_STEP(1);
        }
#undef GRU_STEP

        {
            f32x4 v0;
#pragma unroll
            for (int r = 0; r < 4; r++) v0[r] = hreg[r];
            *(f32x4*)(hstate + ((size_t)(blk * 8 + w) * 64 + lane) * 4) = v0;
        }

        if (doFC) {
            float fw = fcW[32 * w + hi * 16 + lm];
            f32x4 pv;
#pragma unroll
            for (int r = 0; r < 4; r++) pv[r] = hreg[r] * fw;
            __syncthreads();   // shA reads done before shred alias write
            *(f32x4*)(shred + (size_t)(w * 64 + lane) * 4) = pv;
            __syncthreads();
            if (tid < 8) {
                int qq = tid >> 2, rr2 = tid & 3;
                float a = fcb[0];
                for (int ww = 0; ww < 8; ww++)
                    for (int l2 = 0; l2 < 16; l2++)
                        a += shred[(ww * 64 + qq * 16 + l2) * 4 + rr2]
                           + shred[(ww * 64 + 32 + qq * 16 + l2) * 4 + rr2];
                out[blk * 8 + tid] = a;
            }
        }
    } else if (bid < 96) {
        // ================= B0: xg0t(cb) = [x|meta] @ Wih0^T + bih0 (+bhh0 r,z) =================
        const int cb = k + 1;
        if (cb < 0 || cb >= NCH) return;
        _Float16* xg0 = (cb & 1) ? xg0b : xg0a;
        const int fb = bid - 64;                  // octet 0..31
        float* Wb = (float*)smem;                 // 6144 W + 768 bias
        for (int i = tid; i < 6912; i += 512)
            Wb[i] = (i < 6144) ? Wih0[i]
                               : (bih0[i - 6144] + ((i - 6144) < 512 ? bhh0[i - 6144] : 0.f));
        __syncthreads();
        const int sub = tid >> 8;                 // step-half 0..1
        const int t = tid & 255;
        const int w = t >> 5, l32 = t & 31;
        const int qc = l32 >> 4, lm = l32 & 15;

        float Wr[6][8], br[6];
#pragma unroll
        for (int g3 = 0; g3 < 3; g3++)
#pragma unroll
            for (int tp = 0; tp < 2; tp++) {
                int n = g3 * 256 + 32 * w + 16 * tp + lm;
                int j6 = g3 * 2 + tp;
#pragma unroll
                for (int kk = 0; kk < 8; kk++) Wr[j6][kk] = Wb[n * 8 + kk];
                br[j6] = Wb[6144 + n];
            }
        const int b0 = fb * 8 + qc * 4;
        float4 mv[4];
#pragma unroll
        for (int r = 0; r < 4; r++) mv[r] = *(const float4*)(meta + (b0 + r) * 4);

        for (int sl = 0; sl < 16; sl++) {
            int s_local = sub * 16 + sl;
            int s = cb * SCH + s_local;
            float4 xv[4];
#pragma unroll
            for (int r = 0; r < 4; r++)
                xv[r] = *(const float4*)(x + ((size_t)(b0 + r) * 1024 + s) * 4);
            half4_t o[2][3];
#pragma unroll
            for (int g3 = 0; g3 < 3; g3++)
#pragma unroll
            for (int tp = 0; tp < 2; tp++) {
                    int j6 = g3 * 2 + tp;
#pragma unroll
                    for (int r = 0; r < 4; r++) {
                        float v = br[j6]
                            + xv[r].x * Wr[j6][0] + xv[r].y * Wr[j6][1]
                            + xv[r].z * Wr[j6][2] + xv[r].w * Wr[j6][3]
                            + mv[r].x * Wr[j6][4] + mv[r].y * Wr[j6][5]
                            + mv[r].z * Wr[j6][6] + mv[r].w * Wr[j6][7];
                        o[tp][g3][r] = (_Float16)v;
                    }
                }
            _Float16* dst = xg0 + ((size_t)(s_local * 32 + fb) * 8 + w) * 768;
#pragma unroll
            for (int tp = 0; tp < 2; tp++) {
                int slot4 = (l32 + tp * 32) * 4;
#pragma unroll
                for (int g3 = 0; g3 < 3; g3++)
                    *(half4_t*)(dst + g3 * 256 + slot4) = o[tp][g3];
            }
        }
    } else {
        // ================= B1: xg1t(c1) = h0(c1) @ Wih1^T + bih1 (+bhh1 r,z) =================
        const int c1 = k - 1;
        if (c1 < 0 || c1 >= NCH) return;
        const _Float16* hof = (c1 & 1) ? hout1 : hout0;
        _Float16* xg1 = (c1 & 1) ? xg1b : xg1a;
        const int fb = bid - 96;                  // 0..127
        const int s_ch = fb >> 2;                 // source step of hout
        const int bb8 = (fb & 3) * 8;             // base batch-octet
        _Float16* Ah = (_Float16*)smem;           // [64 rows][264 cols] halfs (pad 8)

        // stage hout slab (64 batch rows x 256 cols) with transpose into LDS
#pragma unroll
        for (int i = 0; i < 8; i++) {
            int u = i * 512 + tid;                // 4096 units = 16 row-quads x 256 cols
            int rq = u >> 8, c = u & 255;
            int blk8 = bb8 + (rq >> 1), qh = rq & 1;
            int wc = c >> 5, hic = (c >> 4) & 1, lmc = c & 15;
            half4_t hv = *(const half4_t*)(hof +
                (((size_t)(s_ch * 32 + blk8) * 8 + wc) * 64 + hic * 32 + qh * 16 + lmc) * 4);
#pragma unroll
            for (int r2 = 0; r2 < 4; r2++)
                Ah[(rq * 4 + r2) * 264 + c] = hv[r2];
        }
        __syncthreads();

        const int th = tid >> 8;                  // m-tile pair 0..1
        const int t = tid & 255;
        const int wv = t >> 6, lane = t & 63;
        const int q = lane >> 4, lm = lane & 15;

        float bias[12];
#pragma unroll
        for (int j = 0; j < 12; j++) {
            int n = (wv * 12 + j) * 16 + lm;
            bias[j] = bih1[n] + (n < 512 ? bhh1[n] : 0.f);
        }
        f32x4 acc[2][12] = {};
#pragma unroll
        for (int kt = 0; kt < 8; kt++) {
            half8 af[2], bf[12];
#pragma unroll
            for (int i = 0; i < 2; i++)
                af[i] = *(const half8*)(&Ah[((th * 2 + i) * 16 + lm) * 264 + kt * 32 + q * 8]);
#pragma unroll
            for (int j = 0; j < 12; j++)
                bf[j] = *(const half8*)(Wi1frag + (size_t)((kt * 48 + wv * 12 + j) * 64 + lane) * 8);
#pragma unroll
            for (int i = 0; i < 2; i++)
#pragma unroll
                for (int j = 0; j < 12; j++)
                    acc[i][j] = __builtin_amdgcn_mfma_f32_16x16x32_f16(af[i], bf[j], acc[i][j], 0, 0, 0);
        }
#pragma unroll
        for (int i = 0; i < 2; i++) {
            int tt = fb * 4 + th * 2 + i, s = tt >> 4, bt = tt & 15;
            int blkw = bt * 2 + (q >> 1), qc2 = q & 1;
#pragma unroll
            for (int j = 0; j < 12; j++) {
                int n = (wv * 12 + j) * 16 + lm;
                int g3 = n >> 8, nn = n & 255;
                int wc2 = nn >> 5, tp = (nn >> 4) & 1, lmc2 = nn & 15;
                half4_t v;
#pragma unroll
                for (int r = 0; r < 4; r++) v[r] = (_Float16)(acc[i][j][r] + bias[j]);
                *(half4_t*)(xg1 + ((size_t)(s * 32 + blkw) * 8 + wc2) * 768
                                 + g3 * 256 + (qc2 * 16 + lmc2 + tp * 32) * 4) = v;
            }
        }
    }
}

extern "C" void kernel_launch(void* const* d_in, const int* in_sizes, int n_in,
                              void* d_out, int out_size, void* d_ws, size_t ws_size,
                              hipStream_t stream) {
    const float* x    = (const float*)d_in[0];
    const float* meta = (const float*)d_in[1];
    const float* Wih0 = (const float*)d_in[2];
    const float* Whh0 = (const float*)d_in[3];
    const float* bih0 = (const float*)d_in[4];
    const float* bhh0 = (const float*)d_in[5];
    const float* Wih1 = (const float*)d_in[6];
    const float* Whh1 = (const float*)d_in[7];
    const float* bih1 = (const float*)d_in[8];
    const float* bhh1 = (const float*)d_in[9];
    const float* fcW  = (const float*)d_in[10];
    const float* fcb  = (const float*)d_in[11];
    float* out = (float*)d_out;

    char* ws = (char*)d_ws;
    _Float16* Wfrag0  = (_Float16*)(ws + 0);
    _Float16* Wfrag1  = (_Float16*)(ws + 393216);
    _Float16* Wi1frag = (_Float16*)(ws + 786432);
    float*    hst0    = (float*)(ws + 1179648);
    float*    hst1    = (float*)(ws + 1441792);
    _Float16* hout0   = (_Float16*)(ws + 1703936);
    _Float16* xg0a    = (_Float16*)(ws + 5898240);
    _Float16* xg0b    = (_Float16*)(ws + 18481152);
    _Float16* xg1a    = (_Float16*)(ws + 31064064);
    _Float16* xg1b    = (_Float16*)(ws + 43646976);
    _Float16* hout1   = (_Float16*)(ws + 56229888);

    prep_kernel<<<288, 256, 0, stream>>>(Whh0, Whh1, Wih1, Wfrag0, Wfrag1, Wi1frag);

    for (int k = -1; k <= NCH + 1; k++) {
        mega_kernel<<<224, 512, 0, stream>>>(
            x, meta, Wih0, bih0, bhh0, Wfrag0, Wfrag1, Wi1frag, bih1, bhh1,
            hst0, hst1, hout0, hout1, xg0a, xg0b, xg1a, xg1b, fcW, fcb, out, k);
    }
}